// Round 16
// baseline (44.610 us; speedup 1.0000x reference)
//
#include <hip/hip_runtime.h>
#include <hip/hip_bf16.h>

#define D_DIM 256
#define K_CODES 1024
#define N_ROWS (32 * 1024)
#define BLOCK_ROWS 32                 // rows per block (2 rg x 16)
#define NBLK (N_ROWS / BLOCK_ROWS)    // 1024 blocks -> 3/CU (LDS-capped)
#define STEPS 32                      // 16-code fp8 tiles per kg (512 codes)
#define TILE_I64 520                  // 512 frag i64 (4KB) + 8 i64 (en 64B)

typedef __attribute__((ext_vector_type(4))) float f32x4;
typedef __attribute__((ext_vector_type(2))) long i64x2;
typedef long i64;

#define MFMA8 __builtin_amdgcn_mfma_f32_16x16x32_fp8_fp8
#define CVT8 __builtin_amdgcn_cvt_pk_fp8_f32

static __device__ __forceinline__ void gload_lds16(const void* g, void* s) {
    __builtin_amdgcn_global_load_lds(
        (const __attribute__((address_space(1))) void*)g,
        (__attribute__((address_space(3))) void*)s, 16, 0, 0);
}
static __device__ __forceinline__ void gload_lds4(const void* g, void* s) {
    __builtin_amdgcn_global_load_lds(
        (const __attribute__((address_space(1))) void*)g,
        (__attribute__((address_space(3))) void*)s, 4, 0, 0);
}

static __device__ __forceinline__ i64 pack_fp8x8(float4 p, float4 q, float S) {
    int w0 = CVT8(p.x * S, p.y * S, 0, false);
    w0     = CVT8(p.z * S, p.w * S, w0, true);
    int w1 = CVT8(q.x * S, q.y * S, 0, false);
    w1     = CVT8(q.z * S, q.w * S, w1, true);
    return ((i64)(unsigned)w1 << 32) | (unsigned)w0;
}

// ---------------------------------------------------------------- prep
// (a) enorm[k] = ||E[k]||^2 (f32 exact); (b) Eb8 = fp8(-1024*E), B-frag
// order, kk-PAIRED: i64 idx(t16,kk,l) = t16*512 + (kk>>1)*128 + l*2 + (kk&1)
__global__ __launch_bounds__(256) void vq_prep(const float* __restrict__ E,
                                               float* __restrict__ enorm,
                                               i64* __restrict__ Eb8) {
    int wave = threadIdx.x >> 6;
    int lane = threadIdx.x & 63;
    int k = blockIdx.x * 4 + wave;               // [0,1024)
    const float4 v = *reinterpret_cast<const float4*>(E + k * D_DIM + lane * 4);
    float s = v.x * v.x + v.y * v.y + v.z * v.z + v.w * v.w;
    #pragma unroll
    for (int off = 32; off; off >>= 1) s += __shfl_xor(s, off, 64);
    if (lane == 0) enorm[k] = s;

    if (blockIdx.x < 128) {
        int g = blockIdx.x * 256 + threadIdx.x;  // [0, 32768)
        int t = g >> 9;
        int kk = (g >> 6) & 7;
        int l = g & 63;
        int code = t * 16 + (l & 15);
        int d0 = kk * 32 + ((l >> 4) << 3);
        const float* src = E + (size_t)code * D_DIM + d0;
        float4 v0 = *reinterpret_cast<const float4*>(src);
        float4 v1 = *reinterpret_cast<const float4*>(src + 4);
        Eb8[t * 512 + ((kk >> 1) << 7) + l * 2 + (kk & 1)] =
            pack_fp8x8(v0, v1, -1024.0f);
    }
}

// ---------------------------------------------------------------- main
// R14 structure + coalesced X prologue, m173-verified pattern only:
// ONE global_load_lds per row (row uniform per instruction; lane l sources
// 16B chunk l^(r&7) of the row -> whole 1024B row lands linearly in its
// 16KB Xs slot). Two groups of 16 rows time-share Xs: stage g0 -> rg0
// waves pack -> stage g1 -> rg1 waves pack, barrier-separated. Fragment
// reads use chunk cs^(lr&7) (bank-XOR isomorphic to m201's st_16x32).
__global__ __launch_bounds__(256, 3) void vq_main(const float* __restrict__ X,
                                                  const float* __restrict__ E,
                                                  const float* __restrict__ enorm,
                                                  const i64* __restrict__ Eb8,
                                                  float* __restrict__ outq,
                                                  float* __restrict__ lpart) {
    __shared__ i64   Bt[2][3][TILE_I64];   // ~24.4 KB
    __shared__ i64   Xs[16 * 128];         // 16 KB: 16 rows x 1024B
    __shared__ float mvs[2][BLOCK_ROWS];
    __shared__ int   mis[2][BLOCK_ROWS];
    __shared__ float fxn[BLOCK_ROWS];

    const int tid = threadIdx.x;
    const int w   = tid >> 6;
    const int kg  = w >> 1;       // code half
    const int rg  = w & 1;        // row half
    const int l   = tid & 63;
    const int lr  = l & 15;
    const int lk  = l >> 4;
    const int row0 = blockIdx.x * BLOCK_ROWS;

    // B staging: 3 uniform loads/wave (2 frag chunks + en), same as R13/R14
#define STAGE(T)                                                              \
    do {                                                                      \
        const int t16_ = kg * STEPS + (T);                                    \
        i64* bb = &Bt[kg][(T) % 3][0];                                        \
        _Pragma("unroll")                                                     \
        for (int it = 0; it < 2; ++it) {                                      \
            const int seg = rg * 2 + it;                                      \
            gload_lds16(Eb8 + (size_t)t16_ * 512 + seg * 128 + l * 2,         \
                        bb + seg * 128);                                      \
        }                                                                     \
        if (l < 16) gload_lds4(enorm + t16_ * 16 + l, bb + 512);              \
    } while (0)

    // X staging, group G: wave w stages block-local rows G*16 + w*4 .. +4,
    // ONE instruction per row; lane l sources chunk l^(r&7); dest linear.
#define XSTAGE(G)                                                             \
    do {                                                                      \
        _Pragma("unroll")                                                     \
        for (int rr = 0; rr < 4; ++rr) {                                      \
            const int slot = w * 4 + rr;                                      \
            const int r_   = (G) * 16 + slot;                                 \
            const int cs_  = l ^ (r_ & 7);                                    \
            gload_lds16(X + (size_t)(row0 + r_) * D_DIM + cs_ * 4,            \
                        &Xs[slot * 128]);                                     \
        }                                                                     \
    } while (0)

    // pack this wave's 16 rows (slot = lr) from Xs into fp8 A-frags + norm
#define XPACK                                                                 \
    do {                                                                      \
        _Pragma("unroll")                                                     \
        for (int kk = 0; kk < 8; ++kk) {                                      \
            const int c0 = (kk * 8 + lk * 2) ^ (lr & 7);                      \
            const int c1 = (kk * 8 + lk * 2 + 1) ^ (lr & 7);                  \
            float4 p = *reinterpret_cast<const float4*>(&Xf[lr * 256 + c0 * 4]); \
            float4 q = *reinterpret_cast<const float4*>(&Xf[lr * 256 + c1 * 4]); \
            xn += p.x * p.x + p.y * p.y + p.z * p.z + p.w * p.w               \
                + q.x * q.x + q.y * q.y + q.z * q.z + q.w * q.w;              \
            a[kk] = pack_fp8x8(p, q, 1.0f);                                   \
        }                                                                     \
        xn += __shfl_xor(xn, 16, 64);                                         \
        xn += __shfl_xor(xn, 32, 64);                                         \
    } while (0)

    STAGE(0);
    STAGE(1);
    XSTAGE(0);

    const float* Xf = reinterpret_cast<const float*>(Xs);
    i64   a[8];
    float xn = 0.0f;

    __syncthreads();          // group-0 rows + B0/B1 landed (vmcnt drained)
    if (rg == 0) XPACK;
    __syncthreads();          // all group-0 reads retired
    XSTAGE(1);
    __syncthreads();          // group-1 rows landed
    if (rg == 1) XPACK;

    float minv[4];
    int   mini[4];
    #pragma unroll
    for (int i = 0; i < 4; ++i) { minv[i] = INFINITY; mini[i] = 0; }

    const float inv = 1.0f / 512.0f;   // undo -1024 scale -> -2 x.e

    #pragma unroll 1
    for (int t = 0; t < STEPS; ++t) {
        if (t < STEPS - 1) { asm volatile("s_waitcnt vmcnt(3)" ::: "memory"); }
        else               { asm volatile("s_waitcnt vmcnt(0)" ::: "memory"); }
        __builtin_amdgcn_s_barrier();        // both rg halves of tile t landed
        __builtin_amdgcn_sched_barrier(0);   // reads stay below the wait

        const int buf = t % 3;
        i64x2 bp[4];
        #pragma unroll
        for (int p = 0; p < 4; ++p)
            bp[p] = *reinterpret_cast<const i64x2*>(&Bt[kg][buf][p * 128 + l * 2]);
        const float en = reinterpret_cast<const float*>(&Bt[kg][buf][512])[lr];

        if (t < STEPS - 2) STAGE(t + 2);   // into buf (t+2)%3

        f32x4 acc = {0, 0, 0, 0};
        #pragma unroll
        for (int kk = 0; kk < 8; ++kk)
            acc = MFMA8(a[kk], bp[kk >> 1][kk & 1], acc, 0, 0, 0);

        const int idx = (kg * STEPS + t) * 16 + lr;
        #pragma unroll
        for (int i = 0; i < 4; ++i) {
            float s = fmaf(acc[i], inv, en);
            if (s < minv[i]) { minv[i] = s; mini[i] = idx; }
        }
    }
#undef STAGE
#undef XSTAGE
#undef XPACK

    // ---- reduce over the 16 code-lanes (first-min tie-break, butterfly)
    #pragma unroll
    for (int off = 8; off >= 1; off >>= 1) {
        #pragma unroll
        for (int i = 0; i < 4; ++i) {
            float ov = __shfl_xor(minv[i], off, 64);
            int   oi = __shfl_xor(mini[i], off, 64);
            if (ov < minv[i] || (ov == minv[i] && oi < mini[i])) {
                minv[i] = ov; mini[i] = oi;
            }
        }
    }

    // ---- publish: wave covers rows rg*16 + lk*4 + i (lanes lr==0)
    if (lr == 0) {
        #pragma unroll
        for (int i = 0; i < 4; ++i) {
            mvs[kg][rg * 16 + lk * 4 + i] = minv[i];
            mis[kg][rg * 16 + lk * 4 + i] = mini[i];
        }
    }
    if (kg == 0 && l < 16) fxn[rg * 16 + l] = xn;
    __syncthreads();

    // ---- merge kg halves + gather E[idx] -> outq (wave w: rows [w*8,+8))
    #pragma unroll
    for (int rr = 0; rr < 8; ++rr) {
        const int r = w * 8 + rr;
        // kg0 indices < kg1 indices: strict < keeps first-occurrence min
        const int idx = (mvs[1][r] < mvs[0][r]) ? mis[1][r] : mis[0][r];
        const float4 qv = *reinterpret_cast<const float4*>(
            E + (size_t)idx * D_DIM + l * 4);
        *reinterpret_cast<float4*>(outq + (size_t)(row0 + r) * D_DIM + l * 4) = qv;
    }

    // ---- loss partial: wave 0 sums (minval + xnorm) over the 32 rows
    if (w == 0) {
        float v = (l < BLOCK_ROWS) ? (fminf(mvs[0][l], mvs[1][l]) + fxn[l]) : 0.0f;
        #pragma unroll
        for (int off = 32; off; off >>= 1) v += __shfl_xor(v, off, 64);
        if (l == 0) lpart[blockIdx.x] = v;
    }
}

// ---------------------------------------------------------------- finalize
// deterministic fold of 1024 block partials -> vq_loss scalar
__global__ __launch_bounds__(256) void vq_finalize(const float* __restrict__ partials,
                                                   float* __restrict__ out_loss) {
    __shared__ float s[256];
    int t = threadIdx.x;
    s[t] = partials[t] + partials[t + 256] + partials[t + 512] + partials[t + 768];
    __syncthreads();
    #pragma unroll
    for (int off = 128; off; off >>= 1) {
        if (t < off) s[t] += s[t + off];
        __syncthreads();
    }
    if (t == 0)
        out_loss[0] = s[0] * (1.25f / (float)((size_t)N_ROWS * D_DIM));
}

// ---------------------------------------------------------------- launch
extern "C" void kernel_launch(void* const* d_in, const int* in_sizes, int n_in,
                              void* d_out, int out_size, void* d_ws, size_t ws_size,
                              hipStream_t stream) {
    const float* X = (const float*)d_in[0];   // latents  [32768, 256] f32
    const float* E = (const float*)d_in[1];   // codebook [1024, 256]  f32
    float* out = (float*)d_out;               // 8388608 quantized + 1 loss

    float* enorm = (float*)d_ws;                          // 1024 f32
    float* lpart = enorm + K_CODES;                       // 1024 f32
    i64*   Eb8   = (i64*)(lpart + 1024);                  // 256 KB fp8 frags

    vq_prep    <<<256,  256, 0, stream>>>(E, enorm, Eb8);
    vq_main    <<<NBLK, 256, 0, stream>>>(X, E, enorm, Eb8, out, lpart);
    vq_finalize<<<1,    256, 0, stream>>>(lpart, out + (size_t)N_ROWS * D_DIM);
}

// Round 17
// 38.522 us; speedup vs baseline: 1.1580x; 1.1580x over previous
//
#include <hip/hip_runtime.h>
#include <hip/hip_bf16.h>

#define D_DIM 256
#define K_CODES 1024
#define N_ROWS (32 * 1024)
#define BLOCK_ROWS 64                 // rows per block (4 waves x 16)
#define NBLK (N_ROWS / BLOCK_ROWS)    // 512 blocks -> 2/CU
#define STEPS 16                      // 64-code steps (full K sweep per wave)

typedef __attribute__((ext_vector_type(4))) float f32x4;
typedef __attribute__((ext_vector_type(2))) long i64x2;
typedef long i64;

#define MFMA8 __builtin_amdgcn_mfma_f32_16x16x32_fp8_fp8
#define CVT8 __builtin_amdgcn_cvt_pk_fp8_f32

static __device__ __forceinline__ void gload_lds16(const void* g, void* s) {
    __builtin_amdgcn_global_load_lds(
        (const __attribute__((address_space(1))) void*)g,
        (__attribute__((address_space(3))) void*)s, 16, 0, 0);
}

static __device__ __forceinline__ i64 pack_fp8x8(float4 p, float4 q, float S) {
    int w0 = CVT8(p.x * S, p.y * S, 0, false);
    w0     = CVT8(p.z * S, p.w * S, w0, true);
    int w1 = CVT8(q.x * S, q.y * S, 0, false);
    w1     = CVT8(q.z * S, q.w * S, w1, true);
    return ((i64)(unsigned)w1 << 32) | (unsigned)w0;
}

// ---------------------------------------------------------------- prep
// (a) enorm1[k] = 1 + ||E[k]||^2 (the +1 keeps min-keys positive);
// (b) Eb8 = fp8(-1024*E), B-frag order, kk-PAIRED:
//     i64 idx(t16,kk,l) = t16*512 + (kk>>1)*128 + l*2 + (kk&1)
__global__ __launch_bounds__(256) void vq_prep(const float* __restrict__ E,
                                               float* __restrict__ enorm1,
                                               i64* __restrict__ Eb8) {
    int wave = threadIdx.x >> 6;
    int lane = threadIdx.x & 63;
    int k = blockIdx.x * 4 + wave;               // [0,1024)
    const float4 v = *reinterpret_cast<const float4*>(E + k * D_DIM + lane * 4);
    float s = v.x * v.x + v.y * v.y + v.z * v.z + v.w * v.w;
    #pragma unroll
    for (int off = 32; off; off >>= 1) s += __shfl_xor(s, off, 64);
    if (lane == 0) enorm1[k] = 1.0f + s;

    if (blockIdx.x < 128) {
        int g = blockIdx.x * 256 + threadIdx.x;  // [0, 32768)
        int t = g >> 9;
        int kk = (g >> 6) & 7;
        int l = g & 63;
        int code = t * 16 + (l & 15);
        int d0 = kk * 32 + ((l >> 4) << 3);
        const float* src = E + (size_t)code * D_DIM + d0;
        float4 v0 = *reinterpret_cast<const float4*>(src);
        float4 v1 = *reinterpret_cast<const float4*>(src + 4);
        Eb8[t * 512 + ((kk >> 1) << 7) + l * 2 + (kk & 1)] =
            pack_fp8x8(v0, v1, -1024.0f);
    }
}

// ---------------------------------------------------------------- main
// 512 blocks (2/CU) x 256 thr. Wave w: rows [w*16,+16) x ALL 1024 codes
// -> argmin completes in-wave (no merge). 16 steps of 64-code tiles
// (16 KB), ping-pong LDS, staged one FULL step ahead (vmcnt(0) at step
// top ~free). Min via packed key: bits(1+|e|^2-2xe) | code_idx, positive
// floats -> fminf is argmin with first-occurrence tie-break. X staged
// coalesced (1 DMA/row, XOR chunk swizzle, R16-verified). Fused epilogue.
__global__ __launch_bounds__(256, 2) void vq_main(const float* __restrict__ X,
                                                  const float* __restrict__ E,
                                                  const float* __restrict__ enorm1,
                                                  const i64* __restrict__ Eb8,
                                                  float* __restrict__ outq,
                                                  float* __restrict__ lpart) {
    __shared__ i64   Bq[4096];     // 32 KB: code ping-pong; X rows 32..63 in prologue
    __shared__ i64   Xs2[4096];    // 32 KB: X rows 0..31 in prologue
    __shared__ float En1[1024];    // 4 KB
    __shared__ float fk[BLOCK_ROWS];
    __shared__ float wsum[4];

    const int tid = threadIdx.x;
    const int w   = tid >> 6;
    const int l   = tid & 63;
    const int lr  = l & 15;
    const int lk  = l >> 4;
    const int brow = blockIdx.x * BLOCK_ROWS;
    const int wrow = brow + w * 16;

    // wave w stages step sub-tile (4s+w): 4 uniform DMAs
#define STAGEB(S, BUF)                                                        \
    do {                                                                      \
        const size_t t0 = (size_t)((S) * 4 + w) * 512;                        \
        _Pragma("unroll")                                                     \
        for (int j = 0; j < 4; ++j)                                           \
            gload_lds16(Eb8 + t0 + j * 128 + l * 2,                           \
                        &Bq[(BUF) * 2048 + w * 512 + j * 128]);               \
    } while (0)

    // ---- prologue: stage this wave's 16 X rows (1 DMA/row, chunk l^(r&7))
    i64* xbase = (w < 2) ? &Xs2[w * 16 * 128] : &Bq[(w - 2) * 16 * 128];
    #pragma unroll
    for (int s0 = 0; s0 < 16; ++s0) {
        const int cs_ = l ^ (s0 & 7);
        gload_lds16(X + (size_t)(wrow + s0) * D_DIM + cs_ * 4, xbase + s0 * 128);
    }
    gload_lds16(enorm1 + w * 256 + l * 4, &En1[w * 256]);   // En quarter

    asm volatile("s_waitcnt vmcnt(0)" ::: "memory");   // own rows landed
    __builtin_amdgcn_sched_barrier(0);

    // ---- pack own 16 rows -> fp8 A-frags + row norm (wave-local, no barrier)
    const float* Xf = reinterpret_cast<const float*>(xbase);
    i64   a[8];
    float xn = 0.0f;
    #pragma unroll
    for (int kk = 0; kk < 8; ++kk) {
        const int c0 = (kk * 8 + lk * 2) ^ (lr & 7);
        const int c1 = (kk * 8 + lk * 2 + 1) ^ (lr & 7);
        float4 p = *reinterpret_cast<const float4*>(&Xf[lr * 256 + c0 * 4]);
        float4 q = *reinterpret_cast<const float4*>(&Xf[lr * 256 + c1 * 4]);
        xn += p.x * p.x + p.y * p.y + p.z * p.z + p.w * p.w
            + q.x * q.x + q.y * q.y + q.z * q.z + q.w * q.w;
        a[kk] = pack_fp8x8(p, q, 1.0f);
    }
    xn += __shfl_xor(xn, 16, 64);
    xn += __shfl_xor(xn, 32, 64);   // lanes lk=0: norm of row lr

    __syncthreads();                // all packs done -> Bq free for tiles
    STAGEB(0, 0);

    float mk[4];
    #pragma unroll
    for (int i = 0; i < 4; ++i) mk[i] = INFINITY;

    const float inv = 1.0f / 512.0f;   // undo -1024 scale -> -2 x.e

    #pragma unroll 1
    for (int s = 0; s < STEPS; ++s) {
        asm volatile("s_waitcnt vmcnt(0)" ::: "memory");   // issued 1 step ago
        __builtin_amdgcn_s_barrier();
        __builtin_amdgcn_sched_barrier(0);   // reads stay below the wait

        const int buf = s & 1;
        if (s < STEPS - 1) STAGEB(s + 1, buf ^ 1);

        #pragma unroll
        for (int c2 = 0; c2 < 2; ++c2) {
            const int cs0 = c2 * 2, cs1 = cs0 + 1;
            i64x2 b0[4], b1[4];
            #pragma unroll
            for (int p = 0; p < 4; ++p) {
                b0[p] = *reinterpret_cast<const i64x2*>(
                    &Bq[buf * 2048 + cs0 * 512 + p * 128 + l * 2]);
                b1[p] = *reinterpret_cast<const i64x2*>(
                    &Bq[buf * 2048 + cs1 * 512 + p * 128 + l * 2]);
            }
            f32x4 acc0 = {0, 0, 0, 0}, acc1 = {0, 0, 0, 0};
            #pragma unroll
            for (int kk = 0; kk < 8; ++kk) {
                acc0 = MFMA8(a[kk], b0[kk >> 1][kk & 1], acc0, 0, 0, 0);
                acc1 = MFMA8(a[kk], b1[kk >> 1][kk & 1], acc1, 0, 0, 0);
            }
            const int g0 = (s * 4 + cs0) * 16 + lr;   // global code idx (10b)
            const int g1 = (s * 4 + cs1) * 16 + lr;
            const float e0 = En1[g0];
            const float e1 = En1[g1];
            #pragma unroll
            for (int i = 0; i < 4; ++i) {
                float s0f = fmaf(acc0[i], inv, e0);   // in (0.37, 1.7): positive
                float s1f = fmaf(acc1[i], inv, e1);
                mk[i] = fminf(mk[i], __uint_as_float(__float_as_uint(s0f) | (unsigned)g0));
                mk[i] = fminf(mk[i], __uint_as_float(__float_as_uint(s1f) | (unsigned)g1));
            }
        }
    }
#undef STAGEB

    // ---- reduce keys over the 16 code-lanes (pure fminf butterfly)
    #pragma unroll
    for (int off = 1; off <= 8; off <<= 1)
        #pragma unroll
        for (int i = 0; i < 4; ++i)
            mk[i] = fminf(mk[i], __shfl_xor(mk[i], off, 64));

    // lanes lr==0 hold keys for rows lk*4 + i
    if (lr == 0) {
        #pragma unroll
        for (int i = 0; i < 4; ++i) fk[w * 16 + lk * 4 + i] = mk[i];
    }
    asm volatile("s_waitcnt lgkmcnt(0)" ::: "memory");   // wave-private region
    __builtin_amdgcn_sched_barrier(0);

    // ---- gather E[idx] -> outq for this wave's 16 rows (coalesced 1KB/row)
    #pragma unroll 4
    for (int rr = 0; rr < 16; ++rr) {
        const unsigned u = __float_as_uint(fk[w * 16 + rr]);
        const int idx = (int)(u & 1023u);
        const float4 qv = *reinterpret_cast<const float4*>(
            E + (size_t)idx * D_DIM + l * 4);
        *reinterpret_cast<float4*>(outq + (size_t)(wrow + rr) * D_DIM + l * 4) = qv;
    }

    // ---- loss: per wave sum of (minval + xnorm); key decodes minval+1
    float v = 0.0f;
    if (l < 16) {
        const unsigned u = __float_as_uint(fk[w * 16 + l]);
        v = __uint_as_float(u & ~1023u) - 1.0f + xn;   // |x-e|^2 of row l
    }
    #pragma unroll
    for (int off = 32; off; off >>= 1) v += __shfl_xor(v, off, 64);
    if (l == 0) wsum[w] = v;
    __syncthreads();
    if (tid == 0)
        lpart[blockIdx.x] = wsum[0] + wsum[1] + wsum[2] + wsum[3];
}

// ---------------------------------------------------------------- finalize
// deterministic fold of 512 block partials -> vq_loss scalar
__global__ __launch_bounds__(256) void vq_finalize(const float* __restrict__ partials,
                                                   float* __restrict__ out_loss) {
    __shared__ float s[256];
    int t = threadIdx.x;
    s[t] = partials[t] + partials[t + 256];
    __syncthreads();
    #pragma unroll
    for (int off = 128; off; off >>= 1) {
        if (t < off) s[t] += s[t + off];
        __syncthreads();
    }
    if (t == 0)
        out_loss[0] = s[0] * (1.25f / (float)((size_t)N_ROWS * D_DIM));
}

// ---------------------------------------------------------------- launch
extern "C" void kernel_launch(void* const* d_in, const int* in_sizes, int n_in,
                              void* d_out, int out_size, void* d_ws, size_t ws_size,
                              hipStream_t stream) {
    const float* X = (const float*)d_in[0];   // latents  [32768, 256] f32
    const float* E = (const float*)d_in[1];   // codebook [1024, 256]  f32
    float* out = (float*)d_out;               // 8388608 quantized + 1 loss

    float* enorm1 = (float*)d_ws;                         // 1024 f32 (= 1+|e|^2)
    float* lpart  = enorm1 + K_CODES;                     // 512 f32 (1024 slot)
    i64*   Eb8    = (i64*)(lpart + 1024);                 // 256 KB fp8 frags

    vq_prep    <<<256,  256, 0, stream>>>(E, enorm1, Eb8);
    vq_main    <<<NBLK, 256, 0, stream>>>(X, E, enorm1, Eb8, out, lpart);
    vq_finalize<<<1,    256, 0, stream>>>(lpart, out + (size_t)N_ROWS * D_DIM);
}

// Round 18
// 35.384 us; speedup vs baseline: 1.2608x; 1.0887x over previous
//
#include <hip/hip_runtime.h>
#include <hip/hip_bf16.h>

#define D_DIM 256
#define K_CODES 1024
#define N_ROWS (32 * 1024)
#define BLOCK_ROWS 64                 // rows per block (2 rg x 32)
#define NBLK (N_ROWS / BLOCK_ROWS)    // 512 blocks -> 2/CU
#define STEPS 8                       // 64-code steps per kg (512 codes)

typedef __attribute__((ext_vector_type(4))) float f32x4;
typedef __attribute__((ext_vector_type(2))) long i64x2;
typedef long i64;

#define MFMA8 __builtin_amdgcn_mfma_f32_16x16x32_fp8_fp8
#define CVT8 __builtin_amdgcn_cvt_pk_fp8_f32

static __device__ __forceinline__ void gload_lds16(const void* g, void* s) {
    __builtin_amdgcn_global_load_lds(
        (const __attribute__((address_space(1))) void*)g,
        (__attribute__((address_space(3))) void*)s, 16, 0, 0);
}

static __device__ __forceinline__ i64 pack_fp8x8(float4 p, float4 q, float S) {
    int w0 = CVT8(p.x * S, p.y * S, 0, false);
    w0     = CVT8(p.z * S, p.w * S, w0, true);
    int w1 = CVT8(q.x * S, q.y * S, 0, false);
    w1     = CVT8(q.z * S, q.w * S, w1, true);
    return ((i64)(unsigned)w1 << 32) | (unsigned)w0;
}

// ---------------------------------------------------------------- prep
// (a) enorm1[k] = 1 + ||E[k]||^2 (keeps min-keys positive);
// (b) Eb8 = fp8(-1024*E), B-frag order, kk-PAIRED:
//     i64 idx(t16,kk,l) = t16*512 + (kk>>1)*128 + l*2 + (kk&1)
__global__ __launch_bounds__(256) void vq_prep(const float* __restrict__ E,
                                               float* __restrict__ enorm1,
                                               i64* __restrict__ Eb8) {
    int wave = threadIdx.x >> 6;
    int lane = threadIdx.x & 63;
    int k = blockIdx.x * 4 + wave;               // [0,1024)
    const float4 v = *reinterpret_cast<const float4*>(E + k * D_DIM + lane * 4);
    float s = v.x * v.x + v.y * v.y + v.z * v.z + v.w * v.w;
    #pragma unroll
    for (int off = 32; off; off >>= 1) s += __shfl_xor(s, off, 64);
    if (lane == 0) enorm1[k] = 1.0f + s;

    if (blockIdx.x < 128) {
        int g = blockIdx.x * 256 + threadIdx.x;  // [0, 32768)
        int t = g >> 9;
        int kk = (g >> 6) & 7;
        int l = g & 63;
        int code = t * 16 + (l & 15);
        int d0 = kk * 32 + ((l >> 4) << 3);
        const float* src = E + (size_t)code * D_DIM + d0;
        float4 v0 = *reinterpret_cast<const float4*>(src);
        float4 v1 = *reinterpret_cast<const float4*>(src + 4);
        Eb8[t * 512 + ((kk >> 1) << 7) + l * 2 + (kk & 1)] =
            pack_fp8x8(v0, v1, -1024.0f);
    }
}

// ---------------------------------------------------------------- main
// 512 blocks (2/CU, 8 waves/CU = 2/SIMD) x 256 thr.
// Wave (kg,rg): 32 rows [rg*32,+32) (2 MFMA rowsets) x 512 codes
// [kg*512,+512) in 8 steps of 64 codes (16 KB fp8, ping-pong, rg pair
// co-stages; vmcnt(0)+barrier at step top waits on the stage issued one
// FULL step earlier). Argmin via packed keys (bits(score')|idx, fminf);
// kg halves merge with one fminf per row. X staged coalesced (1 DMA/row,
// XOR chunk swizzle) into the B area, packed to fp8 A-frags before the
// sweep. Fused epilogue: gather f32 E (exact), loss = minval + |x|^2.
__global__ __launch_bounds__(256, 2) void vq_main(const float* __restrict__ X,
                                                  const float* __restrict__ E,
                                                  const float* __restrict__ enorm1,
                                                  const i64* __restrict__ Eb8,
                                                  float* __restrict__ outq,
                                                  float* __restrict__ lpart) {
    __shared__ i64   Bt[2][2][2048];   // 64 KB: B tiles; X rows in prologue
    __shared__ float En1[1024];        // 4 KB
    __shared__ float fk[2][BLOCK_ROWS];
    __shared__ float fxn[BLOCK_ROWS];

    const int tid = threadIdx.x;
    const int w   = tid >> 6;
    const int kg  = w >> 1;       // code half
    const int rg  = w & 1;        // row half
    const int l   = tid & 63;
    const int lr  = l & 15;
    const int lk  = l >> 4;
    const int brow = blockIdx.x * BLOCK_ROWS;

    // rg pair co-stages kg's 64-code tile: 8 x 1KB DMAs per wave
#define STAGEB(S, BUF)                                                        \
    do {                                                                      \
        const size_t t0 = ((size_t)kg * 32 + (S) * 4) * 512 + rg * 1024;      \
        _Pragma("unroll")                                                     \
        for (int j = 0; j < 8; ++j)                                           \
            gload_lds16(Eb8 + t0 + j * 128 + l * 2,                           \
                        &Bt[kg][BUF][rg * 1024 + j * 128]);                   \
    } while (0)

    // ---- prologue: stage 64 X rows into Bt area (1 DMA/row, chunk l^(r&7))
    i64* Xarea = &Bt[0][0][0];
    #pragma unroll
    for (int rr = 0; rr < 16; ++rr) {
        const int r = w * 16 + rr;
        gload_lds16(X + (size_t)(brow + r) * D_DIM + (l ^ (r & 7)) * 4,
                    Xarea + r * 128);
    }
    gload_lds16(enorm1 + w * 256 + l * 4, &En1[w * 256]);

    __syncthreads();   // drains vmcnt: all X rows + En landed

    // ---- pack this wave's 32 rows -> fp8 A-frags (2 rowsets) + row norms
    const float* Xf = reinterpret_cast<const float*>(Xarea);
    i64   a[2][8];
    float xn[2];
    #pragma unroll
    for (int s = 0; s < 2; ++s) {
        const int r = rg * 32 + s * 16 + lr;
        float t = 0.0f;
        #pragma unroll
        for (int kk = 0; kk < 8; ++kk) {
            const int c0 = (kk * 8 + lk * 2) ^ (r & 7);
            const int c1 = (kk * 8 + lk * 2 + 1) ^ (r & 7);
            float4 p = *reinterpret_cast<const float4*>(&Xf[r * 256 + c0 * 4]);
            float4 q = *reinterpret_cast<const float4*>(&Xf[r * 256 + c1 * 4]);
            t += p.x * p.x + p.y * p.y + p.z * p.z + p.w * p.w
               + q.x * q.x + q.y * q.y + q.z * q.z + q.w * q.w;
            a[s][kk] = pack_fp8x8(p, q, 1.0f);
        }
        t += __shfl_xor(t, 16, 64);
        t += __shfl_xor(t, 32, 64);   // all lanes: norm of row r
        xn[s] = t;
    }

    __syncthreads();   // all packs done -> Bt free for B tiles
    STAGEB(0, 0);

    float mk[2][4];
    #pragma unroll
    for (int s = 0; s < 2; ++s)
        #pragma unroll
        for (int i = 0; i < 4; ++i) mk[s][i] = INFINITY;

    const float inv = 1.0f / 512.0f;   // undo -1024 scale -> -2 x.e

    #pragma unroll 1
    for (int t = 0; t < STEPS; ++t) {
        asm volatile("s_waitcnt vmcnt(0)" ::: "memory");   // issued 1 step ago
        __builtin_amdgcn_s_barrier();
        __builtin_amdgcn_sched_barrier(0);   // reads stay below the wait

        const int buf = t & 1;
        if (t < STEPS - 1) STAGEB(t + 1, buf ^ 1);

        #pragma unroll
        for (int cs = 0; cs < 4; ++cs) {
            i64x2 bp[4];
            #pragma unroll
            for (int p = 0; p < 4; ++p)
                bp[p] = *reinterpret_cast<const i64x2*>(
                    &Bt[kg][buf][cs * 512 + p * 128 + l * 2]);

            f32x4 acc0 = {0, 0, 0, 0}, acc1 = {0, 0, 0, 0};
            #pragma unroll
            for (int kk = 0; kk < 8; ++kk) {
                const i64 b = bp[kk >> 1][kk & 1];
                acc0 = MFMA8(a[0][kk], b, acc0, 0, 0, 0);
                acc1 = MFMA8(a[1][kk], b, acc1, 0, 0, 0);
            }

            const int g  = (kg * 32 + t * 4 + cs) * 16 + lr;   // 10-bit idx
            const float en = En1[g];
            #pragma unroll
            for (int i = 0; i < 4; ++i) {
                float s0 = fmaf(acc0[i], inv, en);   // in (0.37,1.7): positive
                float s1 = fmaf(acc1[i], inv, en);
                mk[0][i] = fminf(mk[0][i],
                    __uint_as_float(__float_as_uint(s0) | (unsigned)g));
                mk[1][i] = fminf(mk[1][i],
                    __uint_as_float(__float_as_uint(s1) | (unsigned)g));
            }
        }
    }
#undef STAGEB

    // ---- reduce keys over the 16 code-lanes (pure fminf butterfly)
    #pragma unroll
    for (int off = 1; off <= 8; off <<= 1)
        #pragma unroll
        for (int s = 0; s < 2; ++s)
            #pragma unroll
            for (int i = 0; i < 4; ++i)
                mk[s][i] = fminf(mk[s][i], __shfl_xor(mk[s][i], off, 64));

    // lanes lr==0 hold keys for rows rg*32 + s*16 + lk*4 + i
    if (lr == 0) {
        #pragma unroll
        for (int s = 0; s < 2; ++s)
            #pragma unroll
            for (int i = 0; i < 4; ++i)
                fk[kg][rg * 32 + s * 16 + lk * 4 + i] = mk[s][i];
    }
    if (kg == 0 && l < 16) {
        fxn[rg * 32 + l]      = xn[0];
        fxn[rg * 32 + 16 + l] = xn[1];
    }
    __syncthreads();

    // ---- merge kg halves + gather E[idx] -> outq (wave w: rows [w*16,+16))
    #pragma unroll 4
    for (int rr = 0; rr < 16; ++rr) {
        const int r = w * 16 + rr;
        const float key = fminf(fk[0][r], fk[1][r]);
        const int idx = (int)(__float_as_uint(key) & 1023u);
        const float4 qv = *reinterpret_cast<const float4*>(
            E + (size_t)idx * D_DIM + l * 4);
        *reinterpret_cast<float4*>(outq + (size_t)(brow + r) * D_DIM + l * 4) = qv;
    }

    // ---- loss partial: wave 0 sums (minval + xnorm) over the 64 rows
    if (w == 0) {
        float v = 0.0f;
        if (l < BLOCK_ROWS) {
            const unsigned u = __float_as_uint(fminf(fk[0][l], fk[1][l]));
            v = __uint_as_float(u & ~1023u) - 1.0f + fxn[l];
        }
        #pragma unroll
        for (int off = 32; off; off >>= 1) v += __shfl_xor(v, off, 64);
        if (l == 0) lpart[blockIdx.x] = v;
    }
}

// ---------------------------------------------------------------- finalize
// deterministic fold of 512 block partials -> vq_loss scalar
__global__ __launch_bounds__(256) void vq_finalize(const float* __restrict__ partials,
                                                   float* __restrict__ out_loss) {
    __shared__ float s[256];
    int t = threadIdx.x;
    s[t] = partials[t] + partials[t + 256];
    __syncthreads();
    #pragma unroll
    for (int off = 128; off; off >>= 1) {
        if (t < off) s[t] += s[t + off];
        __syncthreads();
    }
    if (t == 0)
        out_loss[0] = s[0] * (1.25f / (float)((size_t)N_ROWS * D_DIM));
}

// ---------------------------------------------------------------- launch
extern "C" void kernel_launch(void* const* d_in, const int* in_sizes, int n_in,
                              void* d_out, int out_size, void* d_ws, size_t ws_size,
                              hipStream_t stream) {
    const float* X = (const float*)d_in[0];   // latents  [32768, 256] f32
    const float* E = (const float*)d_in[1];   // codebook [1024, 256]  f32
    float* out = (float*)d_out;               // 8388608 quantized + 1 loss

    float* enorm1 = (float*)d_ws;                         // 1024 f32 (= 1+|e|^2)
    float* lpart  = enorm1 + K_CODES;                     // 512 f32 (1024 slot)
    i64*   Eb8    = (i64*)(lpart + 1024);                 // 256 KB fp8 frags

    vq_prep    <<<256,  256, 0, stream>>>(E, enorm1, Eb8);
    vq_main    <<<NBLK, 256, 0, stream>>>(X, E, enorm1, Eb8, out, lpart);
    vq_finalize<<<1,    256, 0, stream>>>(lpart, out + (size_t)N_ROWS * D_DIM);
}